// Round 1
// baseline (999.452 us; speedup 1.0000x reference)
//
#include <hip/hip_runtime.h>
#include <cstdint>
#include <cstddef>

typedef _Float16 f16;
typedef f16   f16x8 __attribute__((ext_vector_type(8)));
typedef float f32x4 __attribute__((ext_vector_type(4)));

#define MFMA16(a, b, c) __builtin_amdgcn_mfma_f32_16x16x32_f16((a), (b), (c), 0, 0, 0)

// async global->LDS, 16B per lane; lds base must be wave-uniform
__device__ __forceinline__ void gload_lds16(const void* g, void* l) {
    __builtin_amdgcn_global_load_lds(
        (const __attribute__((address_space(1))) unsigned int*)g,
        (__attribute__((address_space(3))) unsigned int*)l, 16, 0, 0);
}

// ---------------- prep: f32 -> f16 copy-cast (8 elems/thread) ----------------
__global__ void cvt_f32_f16(const float* __restrict__ in, f16* __restrict__ out, int n8) {
    int i = blockIdx.x * blockDim.x + threadIdx.x;
    if (i >= n8) return;
    const float4 a = ((const float4*)in)[i * 2];
    const float4 b = ((const float4*)in)[i * 2 + 1];
    f16x8 o;
    o[0] = (f16)a.x; o[1] = (f16)a.y; o[2] = (f16)a.z; o[3] = (f16)a.w;
    o[4] = (f16)b.x; o[5] = (f16)b.y; o[6] = (f16)b.z; o[7] = (f16)b.w;
    *(f16x8*)(out + (size_t)i * 8) = o;
}

// ---------------- QKV projection GEMM ----------------
// A: Xb [8192,1024] f16 (row m = t*4+b), B: Wqkv [3072,1024] f16 (rows = out-dim, K-contig, NT gemm)
// epilogue: +bias, (q only) *0.125, scatter to [B,H,T,HD] f16
__global__ __launch_bounds__(256, 3)
void gemm_qkv(const f16* __restrict__ A, const f16* __restrict__ B,
              const float* __restrict__ bq, const float* __restrict__ bk,
              const float* __restrict__ bv,
              f16* __restrict__ q_sp, f16* __restrict__ k_sp, f16* __restrict__ v_sp)
{
    __shared__ f16 Al[128 * 32];
    __shared__ f16 Bl[128 * 32];
    const int tid = threadIdx.x, lane = tid & 63, w = tid >> 6;
    const int wm = w >> 1, wn = w & 1;
    const int m0 = blockIdx.y * 128, n0 = blockIdx.x * 128;
    const int l15 = lane & 15, lh = lane >> 4;

    f32x4 acc[4][4] = {};

    const int c0 = w, c1 = w + 4;               // staging chunk ids (1KB each)
    const int srow0 = c0 * 16 + (lane >> 2);
    const int srow1 = c1 * 16 + (lane >> 2);
    const int scol = (lane & 3) * 8;

    for (int k0 = 0; k0 < 1024; k0 += 32) {
        gload_lds16(A + (size_t)(m0 + srow0) * 1024 + k0 + scol, &Al[c0 * 512]);
        gload_lds16(A + (size_t)(m0 + srow1) * 1024 + k0 + scol, &Al[c1 * 512]);
        gload_lds16(B + (size_t)(n0 + srow0) * 1024 + k0 + scol, &Bl[c0 * 512]);
        gload_lds16(B + (size_t)(n0 + srow1) * 1024 + k0 + scol, &Bl[c1 * 512]);
        __syncthreads();
        f16x8 af[4], bf[4];
        #pragma unroll
        for (int i = 0; i < 4; ++i) {
            af[i] = *(const f16x8*)&Al[(wm * 64 + i * 16 + l15) * 32 + lh * 8];
            bf[i] = *(const f16x8*)&Bl[(wn * 64 + i * 16 + l15) * 32 + lh * 8];
        }
        #pragma unroll
        for (int i = 0; i < 4; ++i)
            #pragma unroll
            for (int j = 0; j < 4; ++j)
                acc[i][j] = MFMA16(af[i], bf[j], acc[i][j]);
        __syncthreads();
    }

    const int seg = n0 >> 10;  // 0=q, 1=k, 2=v (block fully inside one segment)
    const float* bias = (seg == 0) ? bq : (seg == 1) ? bk : bv;
    f16* dst = (seg == 0) ? q_sp : (seg == 1) ? k_sp : v_sp;
    const float scale = (seg == 0) ? 0.125f : 1.0f;

    #pragma unroll
    for (int j = 0; j < 4; ++j) {
        const int n = n0 + wn * 64 + j * 16 + l15;
        const int e = n & 1023, hh = e >> 6, d = e & 63;
        const float bsv = bias[e];
        #pragma unroll
        for (int i = 0; i < 4; ++i) {
            #pragma unroll
            for (int r = 0; r < 4; ++r) {
                const int m = m0 + wm * 64 + i * 16 + lh * 4 + r;
                const int t = m >> 2, bb = m & 3;
                dst[((size_t)(bb * 16 + hh) * 2048 + t) * 64 + d] =
                    (f16)((acc[i][j][r] + bsv) * scale);
            }
        }
    }
}

// ---------------- V transpose: [BH][T][HD] -> [BH][HD][T] ----------------
__global__ __launch_bounds__(256)
void vtrans(const f16* __restrict__ v_sp, f16* __restrict__ v_tp) {
    __shared__ f16 T[64 * 72];
    const int bh = blockIdx.y, t0 = blockIdx.x * 64;
    const int tid = threadIdx.x;
    const f16* src = v_sp + (size_t)bh * 2048 * 64;
    f16* dstp = v_tp + (size_t)bh * 64 * 2048;
    #pragma unroll
    for (int rr = 0; rr < 2; ++rr) {
        int ch = tid + rr * 256;        // 512 chunks of 16B
        int row = ch >> 3, cc = ch & 7;
        *(f16x8*)&T[row * 72 + cc * 8] = *(const f16x8*)&src[(size_t)(t0 + row) * 64 + cc * 8];
    }
    __syncthreads();
    #pragma unroll
    for (int rr = 0; rr < 2; ++rr) {
        int ch = tid + rr * 256;
        int d = ch >> 3, tc = ch & 7;
        f16x8 o;
        #pragma unroll
        for (int j = 0; j < 8; ++j) o[j] = T[(tc * 8 + j) * 72 + d];
        *(f16x8*)&dstp[(size_t)d * 2048 + t0 + tc * 8] = o;
    }
}

// ---------------- fused attention ----------------
// grid (128 q-tiles, 4 batch), 512 thr (8 waves = 8 k-strips of 256)
// per head: S[16,2048] -> LDS(f16, XOR swizzle) -> softmax -> avg(regs) -> PV -> ctx
__global__ __launch_bounds__(512, 2)
void attn_kernel(const f16* __restrict__ q_s, const f16* __restrict__ k_s,
                 const f16* __restrict__ v_t, f16* __restrict__ ctx,
                 float* __restrict__ avg_out)
{
    __shared__ f16 Pbuf[16 * 2048];        // 64 KB, swizzled rows of 4096B
    __shared__ float Ored[8 * 16 * 64];    // 32 KB
    __shared__ float invL[16];

    char* Pc = (char*)Pbuf;
    const int tid = threadIdx.x;
    const int lane = tid & 63;
    const int w = tid >> 6;          // k-strip 0..7
    const int b = blockIdx.y;
    const int t0 = blockIdx.x * 16;
    const int l15 = lane & 15, lh = lane >> 4;
    const int srow = tid >> 5;       // softmax row 0..15
    const int j0 = tid & 31;

    float avg[64];
    #pragma unroll
    for (int i = 0; i < 64; ++i) avg[i] = 0.f;

    for (int h = 0; h < 16; ++h) {
        const f16* Qh = q_s + ((size_t)(b * 16 + h) * 2048 + t0) * 64;
        const f16* Kh = k_s + (size_t)(b * 16 + h) * 2048 * 64;
        const f16* Vh = v_t + (size_t)(b * 16 + h) * 64 * 2048;

        const f16x8 qf0 = *(const f16x8*)(Qh + l15 * 64 + lh * 8);
        const f16x8 qf1 = *(const f16x8*)(Qh + l15 * 64 + 32 + lh * 8);

        // ---- S = Q K^T for this wave's 256-col strip ----
        #pragma unroll
        for (int nt = 0; nt < 16; ++nt) {
            const int kr0 = w * 256 + nt * 16;
            f32x4 s = {0.f, 0.f, 0.f, 0.f};
            const f16x8 kf0 = *(const f16x8*)(Kh + (size_t)(kr0 + l15) * 64 + lh * 8);
            const f16x8 kf1 = *(const f16x8*)(Kh + (size_t)(kr0 + l15) * 64 + 32 + lh * 8);
            s = MFMA16(qf0, kf0, s);
            s = MFMA16(qf1, kf1, s);
            const int col = kr0 + l15;
            #pragma unroll
            for (int r = 0; r < 4; ++r) {
                const int row = lh * 4 + r;
                *(f16*)(Pc + row * 4096 + ((col * 2) ^ ((row & 7) << 4))) = (f16)s[r];
            }
        }
        __syncthreads();

        // ---- softmax over full row (32 threads/row, 64 elems each) ----
        float mx = -1e30f;
        #pragma unroll
        for (int i = 0; i < 64; ++i) {
            const int col = j0 + i * 32;
            float x = (float)*(const f16*)(Pc + srow * 4096 + ((col * 2) ^ ((srow & 7) << 4)));
            mx = fmaxf(mx, x);
        }
        #pragma unroll
        for (int msk = 16; msk; msk >>= 1) mx = fmaxf(mx, __shfl_xor(mx, msk));
        float ssum = 0.f;
        #pragma unroll
        for (int i = 0; i < 64; ++i) {
            const int col = j0 + i * 32;
            char* p = Pc + srow * 4096 + ((col * 2) ^ ((srow & 7) << 4));
            float x = (float)*(const f16*)p;
            float e = __expf(x - mx);
            *(f16*)p = (f16)e;   // store unnormalized; O scaled by inv at the end
            ssum += e;
        }
        #pragma unroll
        for (int msk = 16; msk; msk >>= 1) ssum += __shfl_xor(ssum, msk);
        const float inv = 1.f / ssum;
        if (j0 == 0) invL[srow] = inv;
        __syncthreads();

        // ---- avg_attn accumulate (normalized) ----
        #pragma unroll
        for (int i = 0; i < 64; ++i) {
            const int col = j0 + i * 32;
            float e = (float)*(const f16*)(Pc + srow * 4096 + ((col * 2) ^ ((srow & 7) << 4)));
            avg[i] += e * inv;
        }

        // ---- PV: O[16,64] partial over this wave's k-strip ----
        f32x4 o[4] = {};
        #pragma unroll
        for (int c = 0; c < 8; ++c) {
            const int kk = w * 256 + c * 32;
            const f16x8 a = *(const f16x8*)(Pc + l15 * 4096 +
                                            (((kk + lh * 8) * 2) ^ ((l15 & 7) << 4)));
            #pragma unroll
            for (int dt = 0; dt < 4; ++dt) {
                const f16x8 vf = *(const f16x8*)(Vh + (size_t)(dt * 16 + l15) * 2048 + kk + lh * 8);
                o[dt] = MFMA16(a, vf, o[dt]);
            }
        }
        // ---- cross-wave O reduction ----
        #pragma unroll
        for (int dt = 0; dt < 4; ++dt)
            #pragma unroll
            for (int r = 0; r < 4; ++r)
                Ored[w * 1024 + (lh * 4 + r) * 64 + dt * 16 + l15] = o[dt][r];
        __syncthreads();
        #pragma unroll
        for (int j = 0; j < 2; ++j) {
            const int idx = tid + j * 512;       // 0..1023
            const int q = idx >> 6, d = idx & 63;
            float s2 = 0.f;
            #pragma unroll
            for (int ws_ = 0; ws_ < 8; ++ws_) s2 += Ored[ws_ * 1024 + idx];
            ctx[((size_t)(t0 + q) * 4 + b) * 1024 + h * 64 + d] = (f16)(s2 * invL[q]);
        }
        __syncthreads();   // P / Ored / invL safe for next head
    }

    // ---- write avg_attn ----
    const float s16 = 1.f / 16.f;
    #pragma unroll
    for (int i = 0; i < 64; ++i)
        avg_out[((size_t)b * 2048 + t0 + srow) * 2048 + j0 + i * 32] = avg[i] * s16;
}

// ---------------- output projection GEMM ----------------
__global__ __launch_bounds__(256, 3)
void gemm_out(const f16* __restrict__ A, const f16* __restrict__ B,
              const float* __restrict__ bo, float* __restrict__ out)
{
    __shared__ f16 Al[128 * 32];
    __shared__ f16 Bl[128 * 32];
    const int tid = threadIdx.x, lane = tid & 63, w = tid >> 6;
    const int wm = w >> 1, wn = w & 1;
    const int m0 = blockIdx.y * 128, n0 = blockIdx.x * 128;
    const int l15 = lane & 15, lh = lane >> 4;

    f32x4 acc[4][4] = {};
    const int c0 = w, c1 = w + 4;
    const int srow0 = c0 * 16 + (lane >> 2);
    const int srow1 = c1 * 16 + (lane >> 2);
    const int scol = (lane & 3) * 8;

    for (int k0 = 0; k0 < 1024; k0 += 32) {
        gload_lds16(A + (size_t)(m0 + srow0) * 1024 + k0 + scol, &Al[c0 * 512]);
        gload_lds16(A + (size_t)(m0 + srow1) * 1024 + k0 + scol, &Al[c1 * 512]);
        gload_lds16(B + (size_t)(n0 + srow0) * 1024 + k0 + scol, &Bl[c0 * 512]);
        gload_lds16(B + (size_t)(n0 + srow1) * 1024 + k0 + scol, &Bl[c1 * 512]);
        __syncthreads();
        f16x8 af[4], bf[4];
        #pragma unroll
        for (int i = 0; i < 4; ++i) {
            af[i] = *(const f16x8*)&Al[(wm * 64 + i * 16 + l15) * 32 + lh * 8];
            bf[i] = *(const f16x8*)&Bl[(wn * 64 + i * 16 + l15) * 32 + lh * 8];
        }
        #pragma unroll
        for (int i = 0; i < 4; ++i)
            #pragma unroll
            for (int j = 0; j < 4; ++j)
                acc[i][j] = MFMA16(af[i], bf[j], acc[i][j]);
        __syncthreads();
    }

    #pragma unroll
    for (int j = 0; j < 4; ++j) {
        const int n = n0 + wn * 64 + j * 16 + l15;
        const float bsv = bo[n];
        #pragma unroll
        for (int i = 0; i < 4; ++i) {
            #pragma unroll
            for (int r = 0; r < 4; ++r) {
                const int m = m0 + wm * 64 + i * 16 + lh * 4 + r;
                out[(size_t)m * 1024 + n] = acc[i][j][r] + bsv;
            }
        }
    }
}

extern "C" void kernel_launch(void* const* d_in, const int* in_sizes, int n_in,
                              void* d_out, int out_size, void* d_ws, size_t ws_size,
                              hipStream_t stream) {
    const float* query = (const float*)d_in[0];
    const float* wq = (const float*)d_in[1];
    const float* bq = (const float*)d_in[2];
    const float* wk = (const float*)d_in[3];
    const float* bk = (const float*)d_in[4];
    const float* wv = (const float*)d_in[5];
    const float* bv = (const float*)d_in[6];
    const float* wo = (const float*)d_in[7];
    const float* bo = (const float*)d_in[8];
    float* out = (float*)d_out;

    // workspace layout (f16 elems): total 44M elems = 88 MB
    f16* wsh  = (f16*)d_ws;
    f16* Xb   = wsh;                          // 8M  (query f16; later aliased as ctx)
    f16* Wqkv = wsh + (8u << 20);             // 3M  (wq,wk,wv stacked rows)
    f16* Wo   = wsh + (11u << 20);            // 1M
    f16* q_sp = wsh + (12u << 20);            // 8M  [B,H,T,HD]
    f16* k_sp = wsh + (20u << 20);            // 8M
    f16* v_sp = wsh + (28u << 20);            // 8M
    f16* v_tp = wsh + (36u << 20);            // 8M  [B,H,HD,T]
    f16* ctx  = Xb;                           // alias: Xb dead after gemm_qkv

    cvt_f32_f16<<<4096, 256, 0, stream>>>(query, Xb, 1048576);
    cvt_f32_f16<<<512, 256, 0, stream>>>(wq, Wqkv, 131072);
    cvt_f32_f16<<<512, 256, 0, stream>>>(wk, Wqkv + (1u << 20), 131072);
    cvt_f32_f16<<<512, 256, 0, stream>>>(wv, Wqkv + (2u << 20), 131072);
    cvt_f32_f16<<<512, 256, 0, stream>>>(wo, Wo, 131072);

    gemm_qkv<<<dim3(24, 64), 256, 0, stream>>>(Xb, Wqkv, bq, bk, bv, q_sp, k_sp, v_sp);
    vtrans<<<dim3(32, 64), 256, 0, stream>>>(v_sp, v_tp);
    attn_kernel<<<dim3(128, 4), 512, 0, stream>>>(q_sp, k_sp, v_tp, ctx,
                                                  out + 8388608 /* avg_attn */);
    gemm_out<<<dim3(8, 64), 256, 0, stream>>>(ctx, Wo, bo, out);
}